// Round 1
// baseline (272.284 us; speedup 1.0000x reference)
//
#include <hip/hip_runtime.h>
#include <hip/hip_fp16.h>
#include <cstdint>

typedef __attribute__((ext_vector_type(8))) _Float16 half8;
typedef __attribute__((ext_vector_type(4))) _Float16 half4;
typedef __attribute__((ext_vector_type(4))) float f32x4;

__device__ __forceinline__ void gld_lds16(const void* g, void* l) {
  __builtin_amdgcn_global_load_lds(
      (const __attribute__((address_space(1))) unsigned int*)g,
      (__attribute__((address_space(3))) unsigned int*)l, 16, 0, 0);
}

// ---------------- cast fp32 -> fp16 ----------------
__global__ __launch_bounds__(256) void cast_kernel(const float* __restrict__ in,
                                                   _Float16* __restrict__ out, int n4) {
  int i = blockIdx.x * 256 + threadIdx.x;
  if (i < n4) {
    float4 v = ((const float4*)in)[i];
    half4 h;
    h[0] = (_Float16)v.x; h[1] = (_Float16)v.y;
    h[2] = (_Float16)v.z; h[3] = (_Float16)v.w;
    ((half4*)out)[i] = h;
  }
}

// ---------------- GEMM: C[M,N] = A[M,K] * B[N,K]^T ----------------
// EPI 0: scatter to Q(*0.125)/K/V fp16 buffers [bh][s][64]
// EPI 1: fp32 out + bias
template <int EPI>
__global__ __launch_bounds__(256) void gemm_bt(
    const _Float16* __restrict__ A, const _Float16* __restrict__ B, int K,
    _Float16* __restrict__ Qb, _Float16* __restrict__ Kb, _Float16* __restrict__ Vb,
    float* __restrict__ Out, const float* __restrict__ Bias) {
  __shared__ _Float16 Asm[128 * 64];
  __shared__ _Float16 Bsm[128 * 64];
  const int tid = threadIdx.x;
  const int wave = tid >> 6, lane = tid & 63;
  const int l16 = lane & 15, lg = lane >> 4;
  const int m0 = blockIdx.y * 128, n0 = blockIdx.x * 128;
  const int wr = wave >> 1, wc = wave & 1;
  f32x4 acc[4][4] = {};

  for (int k0 = 0; k0 < K; k0 += 64) {
    __syncthreads();
#pragma unroll
    for (int i = 0; i < 4; i++) {
      int c = tid + i * 256;         // 0..1023 chunks of 16B
      int row = c >> 3, cc = c & 7;  // row 0..127, 8 chunks per 64-elem row
      gld_lds16(A + (size_t)(m0 + row) * K + k0 + cc * 8, (char*)Asm + c * 16);
      gld_lds16(B + (size_t)(n0 + row) * K + k0 + cc * 8, (char*)Bsm + c * 16);
    }
    __syncthreads();
#pragma unroll
    for (int kc = 0; kc < 2; kc++) {
      half8 af[4], bf[4];
#pragma unroll
      for (int f = 0; f < 4; f++) {
        af[f] = *(const half8*)(Asm + (wr * 64 + f * 16 + l16) * 64 + kc * 32 + lg * 8);
        bf[f] = *(const half8*)(Bsm + (wc * 64 + f * 16 + l16) * 64 + kc * 32 + lg * 8);
      }
#pragma unroll
      for (int i = 0; i < 4; i++)
#pragma unroll
        for (int j = 0; j < 4; j++)
          acc[i][j] = __builtin_amdgcn_mfma_f32_16x16x32_f16(af[i], bf[j], acc[i][j], 0, 0, 0);
    }
  }

  if (EPI == 0) {
#pragma unroll
    for (int i = 0; i < 4; i++) {
      int mbase = m0 + wr * 64 + i * 16 + lg * 4;
#pragma unroll
      for (int j = 0; j < 4; j++) {
        int n = n0 + wc * 64 + j * 16 + l16;
        int part = n >> 10, f = n & 1023;
        int h = f >> 6, d = f & 63;
        _Float16* dst = (part == 0) ? Qb : ((part == 1) ? Kb : Vb);
        float scale = (part == 0) ? 0.125f : 1.0f;
#pragma unroll
        for (int r = 0; r < 4; r++) {
          int m = mbase + r;
          int b = m >> 11, s = m & 2047;
          dst[(((size_t)b * 16 + h) * 2048 + s) * 64 + d] = (_Float16)(acc[i][j][r] * scale);
        }
      }
    }
  } else {
#pragma unroll
    for (int i = 0; i < 4; i++) {
      int mbase = m0 + wr * 64 + i * 16 + lg * 4;
#pragma unroll
      for (int j = 0; j < 4; j++) {
        int n = n0 + wc * 64 + j * 16 + l16;
        float bias = Bias[n];
#pragma unroll
        for (int r = 0; r < 4; r++) {
          int m = mbase + r;
          Out[(size_t)m * 1024 + n] = acc[i][j][r] + bias;
        }
      }
    }
  }
}

// ---------------- flash attention (prefix-causal) ----------------
// grid: (bh=32, qtile=32); block 256 = 4 waves * 16 q-rows; KVBLK=64
__global__ __launch_bounds__(256) void attn_kernel(
    const _Float16* __restrict__ Qb, const _Float16* __restrict__ Kb,
    const _Float16* __restrict__ Vb, _Float16* __restrict__ AO) {
  __shared__ _Float16 Ks[64 * 64];      // [j][d], XOR-swizzled
  __shared__ _Float16 Vt[64 * 64];      // [d][j], XOR-swizzled (transposed)
  __shared__ _Float16 Ps[4][16 * 64];   // per-wave P [q][j], XOR-swizzled
  const int bh = blockIdx.x;
  const int q0 = blockIdx.y * 64;
  const int tid = threadIdx.x, wave = tid >> 6, lane = tid & 63;
  const int l16 = lane & 15, lg = lane >> 4;
  const int qw = q0 + wave * 16;
  const size_t bhbase = (size_t)bh * 2048 * 64;

  half8 qf[2];
  {
    const _Float16* qp = Qb + bhbase + (size_t)(qw + l16) * 64 + lg * 8;
    qf[0] = *(const half8*)qp;
    qf[1] = *(const half8*)(qp + 32);
  }
  f32x4 oacc[4] = {};
  float mrun[4] = {-1e30f, -1e30f, -1e30f, -1e30f};
  float lrun[4] = {0.f, 0.f, 0.f, 0.f};
  const int kend = (q0 + 64 > 256) ? (q0 + 64) : 256;

  for (int j0 = 0; j0 < kend; j0 += 64) {
    __syncthreads();
#pragma unroll
    for (int i = 0; i < 2; i++) {
      int c = tid + i * 256;        // 512 chunks of 8 fp16
      int r = c >> 3, cc = c & 7;
      size_t gsrc = bhbase + (size_t)(j0 + r) * 64 + cc * 8;
      half8 kv = *(const half8*)(Kb + gsrc);
      *(half8*)((char*)Ks + ((r * 128 + cc * 16) ^ ((r & 7) << 4))) = kv;
      half8 vv = *(const half8*)(Vb + gsrc);
#pragma unroll
      for (int e = 0; e < 8; e++) {
        int d = cc * 8 + e;
        *((_Float16*)((char*)Vt + ((d * 128 + r * 2) ^ ((d & 7) << 4)))) = vv[e];
      }
    }
    __syncthreads();

    // S = Q K^T  (16 rows x 64 keys per wave)
    f32x4 sf[4] = {};
#pragma unroll
    for (int kc = 0; kc < 2; kc++)
#pragma unroll
      for (int jb = 0; jb < 4; jb++) {
        int j = jb * 16 + l16;
        half8 kf = *(const half8*)((char*)Ks +
                    ((j * 128 + (kc * 32 + lg * 8) * 2) ^ ((j & 7) << 4)));
        sf[jb] = __builtin_amdgcn_mfma_f32_16x16x32_f16(qf[kc], kf, sf[jb], 0, 0, 0);
      }

    // prefix-causal mask: visible iff j <= s || j < 256
    if (j0 + 63 >= 256 && j0 + 63 > qw) {
#pragma unroll
      for (int jb = 0; jb < 4; jb++) {
        int j = j0 + jb * 16 + l16;
#pragma unroll
        for (int r = 0; r < 4; r++) {
          int s = qw + lg * 4 + r;
          if (j > s && j >= 256) sf[jb][r] = -1e30f;
        }
      }
    }

    // online softmax (rows live in 16-lane groups, 4 rows/lane as regs)
    float mt[4];
#pragma unroll
    for (int r = 0; r < 4; r++)
      mt[r] = fmaxf(fmaxf(sf[0][r], sf[1][r]), fmaxf(sf[2][r], sf[3][r]));
#pragma unroll
    for (int msk = 1; msk < 16; msk <<= 1)
#pragma unroll
      for (int r = 0; r < 4; r++) mt[r] = fmaxf(mt[r], __shfl_xor(mt[r], msk));

    float corr[4];
#pragma unroll
    for (int r = 0; r < 4; r++) {
      float mn = fmaxf(mrun[r], mt[r]);
      corr[r] = exp2f((mrun[r] - mn) * 1.44269504f);
      mrun[r] = mn;
    }
    float rs[4] = {0.f, 0.f, 0.f, 0.f};
#pragma unroll
    for (int jb = 0; jb < 4; jb++)
#pragma unroll
      for (int r = 0; r < 4; r++) {
        float p = exp2f((sf[jb][r] - mrun[r]) * 1.44269504f);
        rs[r] += p;
        int q = lg * 4 + r;
        *((_Float16*)((char*)&Ps[wave][0] +
                      ((q * 128 + (jb * 16 + l16) * 2) ^ ((q & 7) << 4)))) = (_Float16)p;
      }
#pragma unroll
    for (int msk = 1; msk < 16; msk <<= 1)
#pragma unroll
      for (int r = 0; r < 4; r++) rs[r] += __shfl_xor(rs[r], msk);
#pragma unroll
    for (int r = 0; r < 4; r++) {
      lrun[r] = lrun[r] * corr[r] + rs[r];
#pragma unroll
      for (int db = 0; db < 4; db++) oacc[db][r] *= corr[r];
    }

    // O += P V   (P re-read from LDS in A-fragment layout)
#pragma unroll
    for (int kc = 0; kc < 2; kc++) {
      half8 pf = *(const half8*)((char*)&Ps[wave][0] +
                  ((l16 * 128 + (kc * 32 + lg * 8) * 2) ^ ((l16 & 7) << 4)));
#pragma unroll
      for (int db = 0; db < 4; db++) {
        int d = db * 16 + l16;
        half8 vf = *(const half8*)((char*)Vt +
                    ((d * 128 + (kc * 32 + lg * 8) * 2) ^ ((d & 7) << 4)));
        oacc[db] = __builtin_amdgcn_mfma_f32_16x16x32_f16(pf, vf, oacc[db], 0, 0, 0);
      }
    }
  }

  const int b = bh >> 4, h = bh & 15;
#pragma unroll
  for (int r = 0; r < 4; r++) {
    float inv = 1.0f / lrun[r];
    int s = qw + lg * 4 + r;
#pragma unroll
    for (int db = 0; db < 4; db++)
      AO[((size_t)b * 2048 + s) * 1024 + h * 64 + db * 16 + l16] =
          (_Float16)(oacc[db][r] * inv);
  }
}

// ---------------- launch ----------------
extern "C" void kernel_launch(void* const* d_in, const int* in_sizes, int n_in,
                              void* d_out, int out_size, void* d_ws, size_t ws_size,
                              hipStream_t stream) {
  const float* x      = (const float*)d_in[0];  // (2,2048,1024)
  const float* qkv_w  = (const float*)d_in[1];  // (3072,1024)
  const float* proj_w = (const float*)d_in[2];  // (1024,1024)
  const float* proj_b = (const float*)d_in[3];  // (1024,)
  float* out = (float*)d_out;

  char* ws = (char*)d_ws;
  _Float16* Xh = (_Float16*)(ws);                      // 4096x1024
  _Float16* Wq = (_Float16*)(ws + ((size_t)8 << 20));  // 3072x1024
  _Float16* Wp = (_Float16*)(ws + ((size_t)14 << 20)); // 1024x1024
  _Float16* Qb = (_Float16*)(ws + ((size_t)16 << 20)); // 32x2048x64
  _Float16* Kb = (_Float16*)(ws + ((size_t)24 << 20));
  _Float16* Vb = (_Float16*)(ws + ((size_t)32 << 20));
  _Float16* AO = (_Float16*)(ws + ((size_t)40 << 20)); // 4096x1024

  cast_kernel<<<4096, 256, 0, stream>>>(x, Xh, 4096 * 1024 / 4);
  cast_kernel<<<3072, 256, 0, stream>>>(qkv_w, Wq, 3072 * 1024 / 4);
  cast_kernel<<<1024, 256, 0, stream>>>(proj_w, Wp, 1024 * 1024 / 4);

  gemm_bt<0><<<dim3(24, 32), 256, 0, stream>>>(Xh, Wq, 1024, Qb, Kb, Vb, nullptr, nullptr);
  attn_kernel<<<dim3(32, 32), 256, 0, stream>>>(Qb, Kb, Vb, AO);
  gemm_bt<1><<<dim3(8, 32), 256, 0, stream>>>(AO, Wp, 1024, nullptr, nullptr, nullptr, out, proj_b);
}

// Round 4
// 246.605 us; speedup vs baseline: 1.1041x; 1.1041x over previous
//
#include <hip/hip_runtime.h>
#include <cstdint>

typedef __attribute__((ext_vector_type(8))) _Float16 half8;
typedef __attribute__((ext_vector_type(4))) _Float16 half4;
typedef __attribute__((ext_vector_type(2))) __fp16 fp16x2;
typedef __attribute__((ext_vector_type(4))) float f32x4;

union H8 { half8 v; unsigned u[4]; };
union H2U { fp16x2 h; unsigned u; };

__device__ __forceinline__ void gld_lds16(const void* g, void* l) {
  __builtin_amdgcn_global_load_lds(
      (const __attribute__((address_space(1))) unsigned int*)g,
      (__attribute__((address_space(3))) unsigned int*)l, 16, 0, 0);
}

// ---------------- cast fp32 -> fp16 ----------------
__global__ __launch_bounds__(256) void cast_kernel(const float* __restrict__ in,
                                                   _Float16* __restrict__ out, int n4) {
  int i = blockIdx.x * 256 + threadIdx.x;
  if (i < n4) {
    float4 v = ((const float4*)in)[i];
    half4 h;
    h[0] = (_Float16)v.x; h[1] = (_Float16)v.y;
    h[2] = (_Float16)v.z; h[3] = (_Float16)v.w;
    ((half4*)out)[i] = h;
  }
}

// ---------------- GEMM: C[M,N] = A[M,K] * B[N,K]^T ----------------
// EPI 0: scatter Q(*0.125)/K to [bh][s][64]; V TRANSPOSED to [bh][d][s']
//        with s' = within-32 bit-permutation (PV contraction order).
// EPI 1: fp32 out + bias
template <int EPI>
__global__ __launch_bounds__(256) void gemm_bt(
    const _Float16* __restrict__ A, const _Float16* __restrict__ B, int K,
    _Float16* __restrict__ Qb, _Float16* __restrict__ Kb, _Float16* __restrict__ VbT,
    float* __restrict__ Out, const float* __restrict__ Bias) {
  __shared__ _Float16 Asm[128 * 64];
  __shared__ _Float16 Bsm[128 * 64];
  const int tid = threadIdx.x;
  const int wave = tid >> 6, lane = tid & 63;
  const int l16 = lane & 15, lg = lane >> 4;
  const int m0 = blockIdx.y * 128, n0 = blockIdx.x * 128;
  const int wr = wave >> 1, wc = wave & 1;
  f32x4 acc[4][4] = {};

  for (int k0 = 0; k0 < K; k0 += 64) {
    __syncthreads();
#pragma unroll
    for (int i = 0; i < 4; i++) {
      int c = tid + i * 256;         // 0..1023 chunks of 16B
      int row = c >> 3, cc = c & 7;  // row 0..127, 8 chunks per 64-elem row
      gld_lds16(A + (size_t)(m0 + row) * K + k0 + cc * 8, (char*)Asm + c * 16);
      gld_lds16(B + (size_t)(n0 + row) * K + k0 + cc * 8, (char*)Bsm + c * 16);
    }
    __syncthreads();
#pragma unroll
    for (int kc = 0; kc < 2; kc++) {
      half8 af[4], bf[4];
#pragma unroll
      for (int f = 0; f < 4; f++) {
        af[f] = *(const half8*)(Asm + (wr * 64 + f * 16 + l16) * 64 + kc * 32 + lg * 8);
        bf[f] = *(const half8*)(Bsm + (wc * 64 + f * 16 + l16) * 64 + kc * 32 + lg * 8);
      }
#pragma unroll
      for (int i = 0; i < 4; i++)
#pragma unroll
        for (int j = 0; j < 4; j++)
          acc[i][j] = __builtin_amdgcn_mfma_f32_16x16x32_f16(af[i], bf[j], acc[i][j], 0, 0, 0);
    }
  }

  if (EPI == 0) {
#pragma unroll
    for (int i = 0; i < 4; i++) {
      int mbase = m0 + wr * 64 + i * 16 + lg * 4;
#pragma unroll
      for (int j = 0; j < 4; j++) {
        int n = n0 + wc * 64 + j * 16 + l16;
        int part = n >> 10, f = n & 1023;
        int h = f >> 6, d = f & 63;
#pragma unroll
        for (int r = 0; r < 4; r++) {
          int m = mbase + r;
          int b = m >> 11, s = m & 2047;
          if (part == 0) {
            Qb[(((size_t)b * 16 + h) * 2048 + s) * 64 + d] = (_Float16)(acc[i][j][r] * 0.125f);
          } else if (part == 1) {
            Kb[(((size_t)b * 16 + h) * 2048 + s) * 64 + d] = (_Float16)acc[i][j][r];
          } else {
            // within-32 j-permutation: orig bits {e2(4),lg(3:2),e01(1:0)} ->
            // slot {lg(4:3), e2(2), e01(1:0)}
            int x = s & 31;
            int sp = (s & ~31) | (x & 3) | (((x >> 2) & 3) << 3) | (((x >> 4) & 1) << 2);
            VbT[(((size_t)b * 16 + h) * 64 + d) * 2048 + sp] = (_Float16)acc[i][j][r];
          }
        }
      }
    }
  } else {
#pragma unroll
    for (int i = 0; i < 4; i++) {
      int mbase = m0 + wr * 64 + i * 16 + lg * 4;
#pragma unroll
      for (int j = 0; j < 4; j++) {
        int n = n0 + wc * 64 + j * 16 + l16;
        float bias = Bias[n];
#pragma unroll
        for (int r = 0; r < 4; r++) {
          int m = mbase + r;
          Out[(size_t)m * 1024 + n] = acc[i][j][r] + bias;
        }
      }
    }
  }
}

// ---------------- flash attention (prefix-causal), v2 ----------------
// grid (32 bh, 16 qtiles reversed); block 256 = 4 waves x 32 q-rows; KVBLK=64.
// Swapped QK^T (S^T layout), O^T accumulation, permuted-j PV (P stays in regs),
// double-buffered LDS staged via global_load_lds with pre-swizzled source.
__global__ __launch_bounds__(256) void attn_kernel(
    const _Float16* __restrict__ Qb, const _Float16* __restrict__ Kb,
    const _Float16* __restrict__ VbT, _Float16* __restrict__ AO) {
  __shared__ _Float16 Ks[2][64 * 64];
  __shared__ _Float16 Vt[2][64 * 64];
  const int bh = blockIdx.x;
  const int q0 = (15 - blockIdx.y) * 128;   // heaviest blocks first
  const int tid = threadIdx.x, wave = tid >> 6, lane = tid & 63;
  const int l16 = lane & 15, lg = lane >> 4;
  const int qw = q0 + wave * 32;
  const size_t bhbase = (size_t)bh * 2048 * 64;
  const _Float16* Kbb = Kb + bhbase;
  const _Float16* Vbb = VbT + bhbase;

  // staging constants (lane-linear LDS dest, pre-swizzled global source)
  const int c0 = tid, c1 = tid + 256;
  const int kofs0 = ((c0 >> 3) * 64) + (((c0 & 7) ^ ((c0 >> 3) & 7)) * 8);
  const int kofs1 = ((c1 >> 3) * 64) + (((c1 & 7) ^ ((c1 >> 3) & 7)) * 8);
  const int vofs0 = ((c0 >> 3) * 2048) + (((c0 & 7) ^ ((c0 >> 3) & 7)) * 8);
  const int vofs1 = ((c1 >> 3) * 2048) + (((c1 & 7) ^ ((c1 >> 3) & 7)) * 8);

  // Q fragments (B-operand rows q = qw + qh*16 + l16)
  half8 qf[2][2];
#pragma unroll
  for (int qh = 0; qh < 2; qh++)
#pragma unroll
    for (int kc = 0; kc < 2; kc++)
      qf[qh][kc] = *(const half8*)(Qb + bhbase +
                    (size_t)(qw + qh * 16 + l16) * 64 + kc * 32 + lg * 8);

  f32x4 oacc[2][4] = {};
  float mrun[2] = {-1e30f, -1e30f}, lrun[2] = {0.f, 0.f};
  const int kend = (q0 + 128 > 256) ? (q0 + 128) : 256;

  // LDS read offsets: byte = row*2048(jb/db) + l16*128 + ((kc*64+lg*16)^xv)
  const int xv = (l16 & 7) << 4;
  const int rb0 = l16 * 128 + ((lg * 16) ^ xv);
  const int rb1 = l16 * 128 + ((64 + lg * 16) ^ xv);

  auto STAGE = [&](int buf, int j0) {
    gld_lds16(Kbb + j0 * 64 + kofs0, (char*)Ks[buf] + c0 * 16);
    gld_lds16(Kbb + j0 * 64 + kofs1, (char*)Ks[buf] + c1 * 16);
    gld_lds16(Vbb + j0 + vofs0, (char*)Vt[buf] + c0 * 16);
    gld_lds16(Vbb + j0 + vofs1, (char*)Vt[buf] + c1 * 16);
  };

  STAGE(0, 0);
  int cur = 0;
  for (int j0 = 0; j0 < kend; j0 += 64) {
    __syncthreads();   // vmcnt(0) drain = wait for cur's stage; barrier
    if (j0 + 64 < kend) STAGE(cur ^ 1, j0 + 64);
    const char* Kc = (const char*)Ks[cur];
    const char* Vc = (const char*)Vt[cur];

    // S^T = K Q^T : lane holds S[q = qw+qh*16+l16][j = j0+jb*16+lg*4+r]
    f32x4 sf[2][4] = {};
#pragma unroll
    for (int kc = 0; kc < 2; kc++) {
      const int rb = kc ? rb1 : rb0;
#pragma unroll
      for (int jb = 0; jb < 4; jb++) {
        half8 kf = *(const half8*)(Kc + jb * 2048 + rb);
        sf[0][jb] = __builtin_amdgcn_mfma_f32_16x16x32_f16(kf, qf[0][kc], sf[0][jb], 0, 0, 0);
        sf[1][jb] = __builtin_amdgcn_mfma_f32_16x16x32_f16(kf, qf[1][kc], sf[1][jb], 0, 0, 0);
      }
    }

    H8 pf[2][2];
#pragma unroll
    for (int qh = 0; qh < 2; qh++) {
      const int qv = qw + qh * 16;
      // prefix-causal mask: visible iff j <= s || j < 256
      if (j0 + 63 >= 256 && j0 + 63 > qv) {
        const int stok = qv + l16;
#pragma unroll
        for (int jb = 0; jb < 4; jb++)
#pragma unroll
          for (int r = 0; r < 4; r++) {
            int j = j0 + jb * 16 + lg * 4 + r;
            if (j > stok && j >= 256) sf[qh][jb][r] = -1e30f;
          }
      }
      // row max: per-lane tree over 16 + 2 shfl (lanes sharing l16)
      float a0 = fmaxf(fmaxf(sf[qh][0][0], sf[qh][0][1]), fmaxf(sf[qh][0][2], sf[qh][0][3]));
      float a1 = fmaxf(fmaxf(sf[qh][1][0], sf[qh][1][1]), fmaxf(sf[qh][1][2], sf[qh][1][3]));
      float a2 = fmaxf(fmaxf(sf[qh][2][0], sf[qh][2][1]), fmaxf(sf[qh][2][2], sf[qh][2][3]));
      float a3 = fmaxf(fmaxf(sf[qh][3][0], sf[qh][3][1]), fmaxf(sf[qh][3][2], sf[qh][3][3]));
      float mt = fmaxf(fmaxf(a0, a1), fmaxf(a2, a3));
      mt = fmaxf(mt, __shfl_xor(mt, 16));
      mt = fmaxf(mt, __shfl_xor(mt, 32));

      float mn = fmaxf(mrun[qh], mt);
      float corr = exp2f((mrun[qh] - mn) * 1.44269504f);
      mrun[qh] = mn;
      const float nb = mn * 1.44269504f;

      float p[16];
#pragma unroll
      for (int jb = 0; jb < 4; jb++)
#pragma unroll
        for (int r = 0; r < 4; r++)
          p[jb * 4 + r] = exp2f(sf[qh][jb][r] * 1.44269504f - nb);

      float s0 = (p[0] + p[1]) + (p[2] + p[3]);
      float s1 = (p[4] + p[5]) + (p[6] + p[7]);
      float s2 = (p[8] + p[9]) + (p[10] + p[11]);
      float s3 = (p[12] + p[13]) + (p[14] + p[15]);
      float rs = (s0 + s1) + (s2 + s3);
      rs += __shfl_xor(rs, 16);
      rs += __shfl_xor(rs, 32);

      lrun[qh] = lrun[qh] * corr + rs;
#pragma unroll
      for (int db = 0; db < 4; db++) {
        oacc[qh][db][0] *= corr; oacc[qh][db][1] *= corr;
        oacc[qh][db][2] *= corr; oacc[qh][db][3] *= corr;
      }
      // pack P to fp16; permuted-j layout makes this the exact B-fragment
#pragma unroll
      for (int kc = 0; kc < 2; kc++) {
        H2U t0, t1, t2, t3;
        t0.h = __builtin_amdgcn_cvt_pkrtz(p[kc * 8 + 0], p[kc * 8 + 1]);
        t1.h = __builtin_amdgcn_cvt_pkrtz(p[kc * 8 + 2], p[kc * 8 + 3]);
        t2.h = __builtin_amdgcn_cvt_pkrtz(p[kc * 8 + 4], p[kc * 8 + 5]);
        t3.h = __builtin_amdgcn_cvt_pkrtz(p[kc * 8 + 6], p[kc * 8 + 7]);
        pf[qh][kc].u[0] = t0.u; pf[qh][kc].u[1] = t1.u;
        pf[qh][kc].u[2] = t2.u; pf[qh][kc].u[3] = t3.u;
      }
    }

    // O^T += V^T P : lane holds O[q = qw+qh*16+l16][d = db*16+lg*4+r]
#pragma unroll
    for (int kc = 0; kc < 2; kc++) {
      const int rb = kc ? rb1 : rb0;
#pragma unroll
      for (int db = 0; db < 4; db++) {
        half8 vf = *(const half8*)(Vc + db * 2048 + rb);
        oacc[0][db] = __builtin_amdgcn_mfma_f32_16x16x32_f16(vf, pf[0][kc].v, oacc[0][db], 0, 0, 0);
        oacc[1][db] = __builtin_amdgcn_mfma_f32_16x16x32_f16(vf, pf[1][kc].v, oacc[1][db], 0, 0, 0);
      }
    }
    cur ^= 1;
  }

  const int b = bh >> 4, h = bh & 15;
#pragma unroll
  for (int qh = 0; qh < 2; qh++) {
    float inv = 1.0f / lrun[qh];
    int q = qw + qh * 16 + l16;
#pragma unroll
    for (int db = 0; db < 4; db++) {
      half4 o;
      o[0] = (_Float16)(oacc[qh][db][0] * inv);
      o[1] = (_Float16)(oacc[qh][db][1] * inv);
      o[2] = (_Float16)(oacc[qh][db][2] * inv);
      o[3] = (_Float16)(oacc[qh][db][3] * inv);
      *(half4*)(AO + ((size_t)b * 2048 + q) * 1024 + h * 64 + db * 16 + lg * 4) = o;
    }
  }
}

// ---------------- launch ----------------
extern "C" void kernel_launch(void* const* d_in, const int* in_sizes, int n_in,
                              void* d_out, int out_size, void* d_ws, size_t ws_size,
                              hipStream_t stream) {
  const float* x      = (const float*)d_in[0];  // (2,2048,1024)
  const float* qkv_w  = (const float*)d_in[1];  // (3072,1024)
  const float* proj_w = (const float*)d_in[2];  // (1024,1024)
  const float* proj_b = (const float*)d_in[3];  // (1024,)
  float* out = (float*)d_out;

  char* ws = (char*)d_ws;
  _Float16* Xh  = (_Float16*)(ws);                      // 4096x1024
  _Float16* Wq  = (_Float16*)(ws + ((size_t)8 << 20));  // 3072x1024
  _Float16* Wp  = (_Float16*)(ws + ((size_t)14 << 20)); // 1024x1024
  _Float16* Qb  = (_Float16*)(ws + ((size_t)16 << 20)); // 32x2048x64
  _Float16* Kb  = (_Float16*)(ws + ((size_t)24 << 20));
  _Float16* VbT = (_Float16*)(ws + ((size_t)32 << 20)); // 32x64x2048 (transposed, j-permuted)
  _Float16* AO  = (_Float16*)(ws + ((size_t)40 << 20)); // 4096x1024

  cast_kernel<<<4096, 256, 0, stream>>>(x, Xh, 4096 * 1024 / 4);
  cast_kernel<<<3072, 256, 0, stream>>>(qkv_w, Wq, 3072 * 1024 / 4);
  cast_kernel<<<1024, 256, 0, stream>>>(proj_w, Wp, 1024 * 1024 / 4);

  gemm_bt<0><<<dim3(24, 32), 256, 0, stream>>>(Xh, Wq, 1024, Qb, Kb, VbT, nullptr, nullptr);
  attn_kernel<<<dim3(32, 16), 256, 0, stream>>>(Qb, Kb, VbT, AO);
  gemm_bt<1><<<dim3(8, 32), 256, 0, stream>>>(AO, Wp, 1024, nullptr, nullptr, nullptr, out, proj_b);
}

// Round 5
// 220.262 us; speedup vs baseline: 1.2362x; 1.1196x over previous
//
#include <hip/hip_runtime.h>
#include <cstdint>

typedef __attribute__((ext_vector_type(8))) _Float16 half8;
typedef __attribute__((ext_vector_type(4))) _Float16 half4;
typedef __attribute__((ext_vector_type(2))) __fp16 fp16x2;
typedef __attribute__((ext_vector_type(4))) float f32x4;

union H8 { half8 v; unsigned u[4]; };
union H2U { fp16x2 h; unsigned u; };

__device__ __forceinline__ void gld_lds16(const void* g, void* l) {
  __builtin_amdgcn_global_load_lds(
      (const __attribute__((address_space(1))) unsigned int*)g,
      (__attribute__((address_space(3))) unsigned int*)l, 16, 0, 0);
}

// ---------------- cast fp32 -> fp16 ----------------
__global__ __launch_bounds__(256) void cast_kernel(const float* __restrict__ in,
                                                   _Float16* __restrict__ out, int n4) {
  int i = blockIdx.x * 256 + threadIdx.x;
  if (i < n4) {
    float4 v = ((const float4*)in)[i];
    half4 h;
    h[0] = (_Float16)v.x; h[1] = (_Float16)v.y;
    h[2] = (_Float16)v.z; h[3] = (_Float16)v.w;
    ((half4*)out)[i] = h;
  }
}

// ---------------- GEMM: C[M,N] = A[M,K] * B[N,K]^T ----------------
// EPI 0: scatter Q(*0.125)/K to [bh][s][64]; V TRANSPOSED to [bh][d][s']
//        with s' = within-32 bit-permutation (PV contraction order).
//        Permutation preserves s low-2-bits -> V writes are half4.
// EPI 1: fp32 out + bias
template <int EPI>
__global__ __launch_bounds__(256) void gemm_bt(
    const _Float16* __restrict__ A, const _Float16* __restrict__ B, int K,
    _Float16* __restrict__ Qb, _Float16* __restrict__ Kb, _Float16* __restrict__ VbT,
    float* __restrict__ Out, const float* __restrict__ Bias) {
  __shared__ _Float16 Asm[128 * 64];
  __shared__ _Float16 Bsm[128 * 64];
  const int tid = threadIdx.x;
  const int wave = tid >> 6, lane = tid & 63;
  const int l16 = lane & 15, lg = lane >> 4;
  const int m0 = blockIdx.y * 128, n0 = blockIdx.x * 128;
  const int wr = wave >> 1, wc = wave & 1;
  f32x4 acc[4][4] = {};

  for (int k0 = 0; k0 < K; k0 += 64) {
    __syncthreads();
#pragma unroll
    for (int i = 0; i < 4; i++) {
      int c = tid + i * 256;         // 0..1023 chunks of 16B
      int row = c >> 3, cc = c & 7;  // row 0..127, 8 chunks per 64-elem row
      gld_lds16(A + (size_t)(m0 + row) * K + k0 + cc * 8, (char*)Asm + c * 16);
      gld_lds16(B + (size_t)(n0 + row) * K + k0 + cc * 8, (char*)Bsm + c * 16);
    }
    __syncthreads();
#pragma unroll
    for (int kc = 0; kc < 2; kc++) {
      half8 af[4], bf[4];
#pragma unroll
      for (int f = 0; f < 4; f++) {
        af[f] = *(const half8*)(Asm + (wr * 64 + f * 16 + l16) * 64 + kc * 32 + lg * 8);
        bf[f] = *(const half8*)(Bsm + (wc * 64 + f * 16 + l16) * 64 + kc * 32 + lg * 8);
      }
#pragma unroll
      for (int i = 0; i < 4; i++)
#pragma unroll
        for (int j = 0; j < 4; j++)
          acc[i][j] = __builtin_amdgcn_mfma_f32_16x16x32_f16(af[i], bf[j], acc[i][j], 0, 0, 0);
    }
  }

  if (EPI == 0) {
#pragma unroll
    for (int i = 0; i < 4; i++) {
      int mbase = m0 + wr * 64 + i * 16 + lg * 4;    // 4-aligned
      int b = mbase >> 11, s = mbase & 2047;
#pragma unroll
      for (int j = 0; j < 4; j++) {
        int n = n0 + wc * 64 + j * 16 + l16;
        int part = n >> 10, f = n & 1023;
        int h = f >> 6, d = f & 63;
        if (part == 2) {
          // within-32 permutation (keeps low 2 bits): one vectorized store
          int x = s & 31;
          int sp = (s & ~31) | (((x >> 2) & 3) << 3) | (((x >> 4) & 1) << 2);
          half4 v;
          v[0] = (_Float16)acc[i][j][0]; v[1] = (_Float16)acc[i][j][1];
          v[2] = (_Float16)acc[i][j][2]; v[3] = (_Float16)acc[i][j][3];
          *(half4*)(VbT + (((size_t)b * 16 + h) * 64 + d) * 2048 + sp) = v;
        } else {
          _Float16* dst = (part == 0) ? Qb : Kb;
          float scale = (part == 0) ? 0.125f : 1.0f;
#pragma unroll
          for (int r = 0; r < 4; r++)
            dst[(((size_t)b * 16 + h) * 2048 + (s + r)) * 64 + d] =
                (_Float16)(acc[i][j][r] * scale);
        }
      }
    }
  } else {
#pragma unroll
    for (int i = 0; i < 4; i++) {
      int mbase = m0 + wr * 64 + i * 16 + lg * 4;
#pragma unroll
      for (int j = 0; j < 4; j++) {
        int n = n0 + wc * 64 + j * 16 + l16;
        float bias = Bias[n];
#pragma unroll
        for (int r = 0; r < 4; r++) {
          int m = mbase + r;
          Out[(size_t)m * 1024 + n] = acc[i][j][r] + bias;
        }
      }
    }
  }
}

// ---------------- flash attention (prefix-causal), v3 ----------------
// grid (32 bh, 16 qtiles reversed); block 512 = 8 waves x 16 q-rows; KVBLK=64.
// Swapped QK^T (S^T layout), O^T accumulation, permuted-j PV (P in regs),
// double-buffered LDS via global_load_lds w/ pre-swizzled source, defer-max.
__global__ __launch_bounds__(512) void attn_kernel(
    const _Float16* __restrict__ Qb, const _Float16* __restrict__ Kb,
    const _Float16* __restrict__ VbT, _Float16* __restrict__ AO) {
  __shared__ _Float16 Ks[2][64 * 64];
  __shared__ _Float16 Vt[2][64 * 64];
  const int bh = blockIdx.x;
  const int q0 = (15 - blockIdx.y) * 128;   // heaviest blocks first
  const int tid = threadIdx.x, wave = tid >> 6, lane = tid & 63;
  const int l16 = lane & 15, lg = lane >> 4;
  const int qw = q0 + wave * 16;
  const size_t bhbase = (size_t)bh * 2048 * 64;
  const _Float16* Kbb = Kb + bhbase;
  const _Float16* Vbb = VbT + bhbase;

  // staging: lane-linear LDS dest, pre-swizzled global source (512 thr = 1 chunk each)
  const int c = tid;
  const int kofs = ((c >> 3) * 64) + (((c & 7) ^ ((c >> 3) & 7)) * 8);
  const int vofs = ((c >> 3) * 2048) + (((c & 7) ^ ((c >> 3) & 7)) * 8);

  // Q fragments (B-operand rows q = qw + l16)
  half8 qf[2];
#pragma unroll
  for (int kc = 0; kc < 2; kc++)
    qf[kc] = *(const half8*)(Qb + bhbase + (size_t)(qw + l16) * 64 + kc * 32 + lg * 8);

  f32x4 oacc[4] = {};
  float mrun = -1e30f, lrun = 0.f;
  const int kend = (q0 + 128 > 256) ? (q0 + 128) : 256;

  // LDS read offsets: byte = row*2048(jb/db) + l16*128 + ((kc*64+lg*16)^xv)
  const int xv = (l16 & 7) << 4;
  const int rb0 = l16 * 128 + ((lg * 16) ^ xv);
  const int rb1 = l16 * 128 + ((64 + lg * 16) ^ xv);

  auto STAGE = [&](int buf, int j0) {
    gld_lds16(Kbb + j0 * 64 + kofs, (char*)Ks[buf] + c * 16);
    gld_lds16(Vbb + j0 + vofs, (char*)Vt[buf] + c * 16);
  };

  STAGE(0, 0);
  int cur = 0;
  for (int j0 = 0; j0 < kend; j0 += 64) {
    __syncthreads();   // vmcnt(0) drain = wait for cur's stage; barrier
    if (j0 + 64 < kend) STAGE(cur ^ 1, j0 + 64);
    const char* Kc = (const char*)Ks[cur];
    const char* Vc = (const char*)Vt[cur];

    // S^T = K Q^T : lane holds S[q = qw+l16][j = j0+jb*16+lg*4+r]
    f32x4 sf[4] = {};
#pragma unroll
    for (int kc = 0; kc < 2; kc++) {
      const int rb = kc ? rb1 : rb0;
#pragma unroll
      for (int jb = 0; jb < 4; jb++) {
        half8 kf = *(const half8*)(Kc + jb * 2048 + rb);
        sf[jb] = __builtin_amdgcn_mfma_f32_16x16x32_f16(kf, qf[kc], sf[jb], 0, 0, 0);
      }
    }

    // prefix-causal mask: visible iff j <= s || j < 256
    if (j0 + 63 >= 256 && j0 + 63 > qw) {
      const int stok = qw + l16;
#pragma unroll
      for (int jb = 0; jb < 4; jb++)
#pragma unroll
        for (int r = 0; r < 4; r++) {
          int j = j0 + jb * 16 + lg * 4 + r;
          if (j > stok && j >= 256) sf[jb][r] = -1e30f;
        }
    }

    // row max: per-lane tree over 16 + 2 shfl (lanes sharing l16)
    float a0 = fmaxf(fmaxf(sf[0][0], sf[0][1]), fmaxf(sf[0][2], sf[0][3]));
    float a1 = fmaxf(fmaxf(sf[1][0], sf[1][1]), fmaxf(sf[1][2], sf[1][3]));
    float a2 = fmaxf(fmaxf(sf[2][0], sf[2][1]), fmaxf(sf[2][2], sf[2][3]));
    float a3 = fmaxf(fmaxf(sf[3][0], sf[3][1]), fmaxf(sf[3][2], sf[3][3]));
    float mt = fmaxf(fmaxf(a0, a1), fmaxf(a2, a3));
    mt = fmaxf(mt, __shfl_xor(mt, 16));
    mt = fmaxf(mt, __shfl_xor(mt, 32));

    // defer-max (T13): skip O-rescale while (mt-mrun)*log2e <= 8
    if (!__all(mt <= mrun + 5.545177f)) {
      float mn = fmaxf(mrun, mt);
      float corr = exp2f((mrun - mn) * 1.44269504f);
      mrun = mn;
      lrun *= corr;
#pragma unroll
      for (int db = 0; db < 4; db++) {
        oacc[db][0] *= corr; oacc[db][1] *= corr;
        oacc[db][2] *= corr; oacc[db][3] *= corr;
      }
    }
    const float nb = mrun * 1.44269504f;

    float p[16];
#pragma unroll
    for (int jb = 0; jb < 4; jb++)
#pragma unroll
      for (int r = 0; r < 4; r++)
        p[jb * 4 + r] = exp2f(sf[jb][r] * 1.44269504f - nb);

    float s0 = (p[0] + p[1]) + (p[2] + p[3]);
    float s1 = (p[4] + p[5]) + (p[6] + p[7]);
    float s2 = (p[8] + p[9]) + (p[10] + p[11]);
    float s3 = (p[12] + p[13]) + (p[14] + p[15]);
    float rs = (s0 + s1) + (s2 + s3);
    rs += __shfl_xor(rs, 16);
    rs += __shfl_xor(rs, 32);
    lrun += rs;

    // pack P to fp16; permuted-j layout makes this the exact B-fragment
    H8 pf[2];
#pragma unroll
    for (int kc = 0; kc < 2; kc++) {
      H2U t0, t1, t2, t3;
      t0.h = __builtin_amdgcn_cvt_pkrtz(p[kc * 8 + 0], p[kc * 8 + 1]);
      t1.h = __builtin_amdgcn_cvt_pkrtz(p[kc * 8 + 2], p[kc * 8 + 3]);
      t2.h = __builtin_amdgcn_cvt_pkrtz(p[kc * 8 + 4], p[kc * 8 + 5]);
      t3.h = __builtin_amdgcn_cvt_pkrtz(p[kc * 8 + 6], p[kc * 8 + 7]);
      pf[kc].u[0] = t0.u; pf[kc].u[1] = t1.u;
      pf[kc].u[2] = t2.u; pf[kc].u[3] = t3.u;
    }

    // O^T += V^T P : lane holds O[q = qw+l16][d = db*16+lg*4+r]
#pragma unroll
    for (int kc = 0; kc < 2; kc++) {
      const int rb = kc ? rb1 : rb0;
#pragma unroll
      for (int db = 0; db < 4; db++) {
        half8 vf = *(const half8*)(Vc + db * 2048 + rb);
        oacc[db] = __builtin_amdgcn_mfma_f32_16x16x32_f16(vf, pf[kc].v, oacc[db], 0, 0, 0);
      }
    }
    cur ^= 1;
  }

  const int b = bh >> 4, h = bh & 15;
  float inv = 1.0f / lrun;
  int q = qw + l16;
#pragma unroll
  for (int db = 0; db < 4; db++) {
    half4 o;
    o[0] = (_Float16)(oacc[db][0] * inv);
    o[1] = (_Float16)(oacc[db][1] * inv);
    o[2] = (_Float16)(oacc[db][2] * inv);
    o[3] = (_Float16)(oacc[db][3] * inv);
    *(half4*)(AO + ((size_t)b * 2048 + q) * 1024 + h * 64 + db * 16 + lg * 4) = o;
  }
}

// ---------------- launch ----------------
extern "C" void kernel_launch(void* const* d_in, const int* in_sizes, int n_in,
                              void* d_out, int out_size, void* d_ws, size_t ws_size,
                              hipStream_t stream) {
  const float* x      = (const float*)d_in[0];  // (2,2048,1024)
  const float* qkv_w  = (const float*)d_in[1];  // (3072,1024)
  const float* proj_w = (const float*)d_in[2];  // (1024,1024)
  const float* proj_b = (const float*)d_in[3];  // (1024,)
  float* out = (float*)d_out;

  char* ws = (char*)d_ws;
  _Float16* Xh  = (_Float16*)(ws);                      // 4096x1024
  _Float16* Wq  = (_Float16*)(ws + ((size_t)8 << 20));  // 3072x1024
  _Float16* Wp  = (_Float16*)(ws + ((size_t)14 << 20)); // 1024x1024
  _Float16* Qb  = (_Float16*)(ws + ((size_t)16 << 20)); // 32x2048x64
  _Float16* Kb  = (_Float16*)(ws + ((size_t)24 << 20));
  _Float16* VbT = (_Float16*)(ws + ((size_t)32 << 20)); // 32x64x2048 (transposed, j-permuted)
  _Float16* AO  = (_Float16*)(ws + ((size_t)40 << 20)); // 4096x1024

  cast_kernel<<<4096, 256, 0, stream>>>(x, Xh, 4096 * 1024 / 4);
  cast_kernel<<<3072, 256, 0, stream>>>(qkv_w, Wq, 3072 * 1024 / 4);
  cast_kernel<<<1024, 256, 0, stream>>>(proj_w, Wp, 1024 * 1024 / 4);

  gemm_bt<0><<<dim3(24, 32), 256, 0, stream>>>(Xh, Wq, 1024, Qb, Kb, VbT, nullptr, nullptr);
  attn_kernel<<<dim3(32, 16), 512, 0, stream>>>(Qb, Kb, VbT, AO);
  gemm_bt<1><<<dim3(8, 32), 256, 0, stream>>>(AO, Wp, 1024, nullptr, nullptr, nullptr, out, proj_b);
}

// Round 6
// 201.212 us; speedup vs baseline: 1.3532x; 1.0947x over previous
//
#include <hip/hip_runtime.h>
#include <cstdint>

typedef __attribute__((ext_vector_type(8))) _Float16 half8;
typedef __attribute__((ext_vector_type(4))) _Float16 half4;
typedef __attribute__((ext_vector_type(2))) __fp16 fp16x2;
typedef __attribute__((ext_vector_type(4))) float f32x4;

union H8 { half8 v; unsigned u[4]; };
union H2U { fp16x2 h; unsigned u; };

__device__ __forceinline__ void gld_lds16(const void* g, void* l) {
  __builtin_amdgcn_global_load_lds(
      (const __attribute__((address_space(1))) unsigned int*)g,
      (__attribute__((address_space(3))) unsigned int*)l, 16, 0, 0);
}

// ---------------- fused cast fp32 -> fp16 (x | qkv_w | proj_w) ----------------
// outputs are contiguous in ws: Xh @0 (4M halfs), Wq @8MB (3M), Wp @14MB (1M)
__global__ __launch_bounds__(256) void cast3_kernel(
    const float* __restrict__ x, const float* __restrict__ w1,
    const float* __restrict__ w2, _Float16* __restrict__ out) {
  int i = blockIdx.x * 256 + threadIdx.x;   // chunk of 4 floats
  const float* src;
  int off;
  if (i < 1048576)      { src = x;  off = i; }
  else if (i < 1835008) { src = w1; off = i - 1048576; }
  else                  { src = w2; off = i - 1835008; }
  float4 v = ((const float4*)src)[off];
  half4 h;
  h[0] = (_Float16)v.x; h[1] = (_Float16)v.y;
  h[2] = (_Float16)v.z; h[3] = (_Float16)v.w;
  ((half4*)out)[i] = h;
}

// ---------------- GEMM: C[M,N] = A[M,K] * B[N,K]^T ----------------
// LDS tiles XOR-swizzled (T2): linear global_load_lds dest + pre-swizzled
// global source chunk; reads apply the same XOR -> 2-way max (free).
// EPI 0: scatter Q(*0.125)/K to [bh][s][64]; V TRANSPOSED to [bh][d][s']
//        with s' = within-32 bit-permutation (PV contraction order).
// EPI 1: fp32 out + bias
template <int EPI>
__global__ __launch_bounds__(256) void gemm_bt(
    const _Float16* __restrict__ A, const _Float16* __restrict__ B, int K,
    _Float16* __restrict__ Qb, _Float16* __restrict__ Kb, _Float16* __restrict__ VbT,
    float* __restrict__ Out, const float* __restrict__ Bias) {
  __shared__ _Float16 Asm[128 * 64];
  __shared__ _Float16 Bsm[128 * 64];
  const int tid = threadIdx.x;
  const int wave = tid >> 6, lane = tid & 63;
  const int l16 = lane & 15, lg = lane >> 4;
  const int m0 = blockIdx.y * 128, n0 = blockIdx.x * 128;
  const int wr = wave >> 1, wc = wave & 1;
  f32x4 acc[4][4] = {};

  // staging source pre-swizzle: chunk cc -> cc ^ (row&7)
  int srow[4], sofs[4];
#pragma unroll
  for (int i = 0; i < 4; i++) {
    int c = tid + i * 256;
    srow[i] = c >> 3;
    sofs[i] = ((c & 7) ^ (srow[i] & 7)) * 8;
  }
  // fragment-read byte offset within row (row&7 == l16&7 for all frags)
  const int rb0 = ((lg) ^ (l16 & 7)) * 16;        // kc=0: chunk = lg
  const int rb1 = ((4 + lg) ^ (l16 & 7)) * 16;    // kc=1: chunk = 4+lg

  for (int k0 = 0; k0 < K; k0 += 64) {
    __syncthreads();
#pragma unroll
    for (int i = 0; i < 4; i++) {
      int c = tid + i * 256;
      gld_lds16(A + (size_t)(m0 + srow[i]) * K + k0 + sofs[i], (char*)Asm + c * 16);
      gld_lds16(B + (size_t)(n0 + srow[i]) * K + k0 + sofs[i], (char*)Bsm + c * 16);
    }
    __syncthreads();
#pragma unroll
    for (int kc = 0; kc < 2; kc++) {
      const int rb = kc ? rb1 : rb0;
      half8 af[4], bf[4];
#pragma unroll
      for (int f = 0; f < 4; f++) {
        af[f] = *(const half8*)((char*)Asm + (wr * 64 + f * 16 + l16) * 128 + rb);
        bf[f] = *(const half8*)((char*)Bsm + (wc * 64 + f * 16 + l16) * 128 + rb);
      }
#pragma unroll
      for (int i = 0; i < 4; i++)
#pragma unroll
        for (int j = 0; j < 4; j++)
          acc[i][j] = __builtin_amdgcn_mfma_f32_16x16x32_f16(af[i], bf[j], acc[i][j], 0, 0, 0);
    }
  }

  if (EPI == 0) {
#pragma unroll
    for (int i = 0; i < 4; i++) {
      int mbase = m0 + wr * 64 + i * 16 + lg * 4;    // 4-aligned
      int b = mbase >> 11, s = mbase & 2047;
#pragma unroll
      for (int j = 0; j < 4; j++) {
        int n = n0 + wc * 64 + j * 16 + l16;
        int part = n >> 10, f = n & 1023;
        int h = f >> 6, d = f & 63;
        if (part == 2) {
          // within-32 permutation (keeps low 2 bits): one vectorized store
          int x = s & 31;
          int sp = (s & ~31) | (((x >> 2) & 3) << 3) | (((x >> 4) & 1) << 2);
          half4 v;
          v[0] = (_Float16)acc[i][j][0]; v[1] = (_Float16)acc[i][j][1];
          v[2] = (_Float16)acc[i][j][2]; v[3] = (_Float16)acc[i][j][3];
          *(half4*)(VbT + (((size_t)b * 16 + h) * 64 + d) * 2048 + sp) = v;
        } else {
          _Float16* dst = (part == 0) ? Qb : Kb;
          float scale = (part == 0) ? 0.125f : 1.0f;
#pragma unroll
          for (int r = 0; r < 4; r++)
            dst[(((size_t)b * 16 + h) * 2048 + (s + r)) * 64 + d] =
                (_Float16)(acc[i][j][r] * scale);
        }
      }
    }
  } else {
#pragma unroll
    for (int i = 0; i < 4; i++) {
      int mbase = m0 + wr * 64 + i * 16 + lg * 4;
#pragma unroll
      for (int j = 0; j < 4; j++) {
        int n = n0 + wc * 64 + j * 16 + l16;
        float bias = Bias[n];
#pragma unroll
        for (int r = 0; r < 4; r++) {
          int m = mbase + r;
          Out[(size_t)m * 1024 + n] = acc[i][j][r] + bias;
        }
      }
    }
  }
}

// ---------------- flash attention (prefix-causal), v3 (unchanged) ----------------
// grid (32 bh, 16 qtiles reversed); block 512 = 8 waves x 16 q-rows; KVBLK=64.
__global__ __launch_bounds__(512) void attn_kernel(
    const _Float16* __restrict__ Qb, const _Float16* __restrict__ Kb,
    const _Float16* __restrict__ VbT, _Float16* __restrict__ AO) {
  __shared__ _Float16 Ks[2][64 * 64];
  __shared__ _Float16 Vt[2][64 * 64];
  const int bh = blockIdx.x;
  const int q0 = (15 - blockIdx.y) * 128;   // heaviest blocks first
  const int tid = threadIdx.x, wave = tid >> 6, lane = tid & 63;
  const int l16 = lane & 15, lg = lane >> 4;
  const int qw = q0 + wave * 16;
  const size_t bhbase = (size_t)bh * 2048 * 64;
  const _Float16* Kbb = Kb + bhbase;
  const _Float16* Vbb = VbT + bhbase;

  const int c = tid;
  const int kofs = ((c >> 3) * 64) + (((c & 7) ^ ((c >> 3) & 7)) * 8);
  const int vofs = ((c >> 3) * 2048) + (((c & 7) ^ ((c >> 3) & 7)) * 8);

  half8 qf[2];
#pragma unroll
  for (int kc = 0; kc < 2; kc++)
    qf[kc] = *(const half8*)(Qb + bhbase + (size_t)(qw + l16) * 64 + kc * 32 + lg * 8);

  f32x4 oacc[4] = {};
  float mrun = -1e30f, lrun = 0.f;
  const int kend = (q0 + 128 > 256) ? (q0 + 128) : 256;

  const int xv = (l16 & 7) << 4;
  const int rb0 = l16 * 128 + ((lg * 16) ^ xv);
  const int rb1 = l16 * 128 + ((64 + lg * 16) ^ xv);

  auto STAGE = [&](int buf, int j0) {
    gld_lds16(Kbb + j0 * 64 + kofs, (char*)Ks[buf] + c * 16);
    gld_lds16(Vbb + j0 + vofs, (char*)Vt[buf] + c * 16);
  };

  STAGE(0, 0);
  int cur = 0;
  for (int j0 = 0; j0 < kend; j0 += 64) {
    __syncthreads();
    if (j0 + 64 < kend) STAGE(cur ^ 1, j0 + 64);
    const char* Kc = (const char*)Ks[cur];
    const char* Vc = (const char*)Vt[cur];

    f32x4 sf[4] = {};
#pragma unroll
    for (int kc = 0; kc < 2; kc++) {
      const int rb = kc ? rb1 : rb0;
#pragma unroll
      for (int jb = 0; jb < 4; jb++) {
        half8 kf = *(const half8*)(Kc + jb * 2048 + rb);
        sf[jb] = __builtin_amdgcn_mfma_f32_16x16x32_f16(kf, qf[kc], sf[jb], 0, 0, 0);
      }
    }

    if (j0 + 63 >= 256 && j0 + 63 > qw) {
      const int stok = qw + l16;
#pragma unroll
      for (int jb = 0; jb < 4; jb++)
#pragma unroll
        for (int r = 0; r < 4; r++) {
          int j = j0 + jb * 16 + lg * 4 + r;
          if (j > stok && j >= 256) sf[jb][r] = -1e30f;
        }
    }

    float a0 = fmaxf(fmaxf(sf[0][0], sf[0][1]), fmaxf(sf[0][2], sf[0][3]));
    float a1 = fmaxf(fmaxf(sf[1][0], sf[1][1]), fmaxf(sf[1][2], sf[1][3]));
    float a2 = fmaxf(fmaxf(sf[2][0], sf[2][1]), fmaxf(sf[2][2], sf[2][3]));
    float a3 = fmaxf(fmaxf(sf[3][0], sf[3][1]), fmaxf(sf[3][2], sf[3][3]));
    float mt = fmaxf(fmaxf(a0, a1), fmaxf(a2, a3));
    mt = fmaxf(mt, __shfl_xor(mt, 16));
    mt = fmaxf(mt, __shfl_xor(mt, 32));

    if (!__all(mt <= mrun + 5.545177f)) {
      float mn = fmaxf(mrun, mt);
      float corr = exp2f((mrun - mn) * 1.44269504f);
      mrun = mn;
      lrun *= corr;
#pragma unroll
      for (int db = 0; db < 4; db++) {
        oacc[db][0] *= corr; oacc[db][1] *= corr;
        oacc[db][2] *= corr; oacc[db][3] *= corr;
      }
    }
    const float nb = mrun * 1.44269504f;

    float p[16];
#pragma unroll
    for (int jb = 0; jb < 4; jb++)
#pragma unroll
      for (int r = 0; r < 4; r++)
        p[jb * 4 + r] = exp2f(sf[jb][r] * 1.44269504f - nb);

    float s0 = (p[0] + p[1]) + (p[2] + p[3]);
    float s1 = (p[4] + p[5]) + (p[6] + p[7]);
    float s2 = (p[8] + p[9]) + (p[10] + p[11]);
    float s3 = (p[12] + p[13]) + (p[14] + p[15]);
    float rs = (s0 + s1) + (s2 + s3);
    rs += __shfl_xor(rs, 16);
    rs += __shfl_xor(rs, 32);
    lrun += rs;

    H8 pf[2];
#pragma unroll
    for (int kc = 0; kc < 2; kc++) {
      H2U t0, t1, t2, t3;
      t0.h = __builtin_amdgcn_cvt_pkrtz(p[kc * 8 + 0], p[kc * 8 + 1]);
      t1.h = __builtin_amdgcn_cvt_pkrtz(p[kc * 8 + 2], p[kc * 8 + 3]);
      t2.h = __builtin_amdgcn_cvt_pkrtz(p[kc * 8 + 4], p[kc * 8 + 5]);
      t3.h = __builtin_amdgcn_cvt_pkrtz(p[kc * 8 + 6], p[kc * 8 + 7]);
      pf[kc].u[0] = t0.u; pf[kc].u[1] = t1.u;
      pf[kc].u[2] = t2.u; pf[kc].u[3] = t3.u;
    }

#pragma unroll
    for (int kc = 0; kc < 2; kc++) {
      const int rb = kc ? rb1 : rb0;
#pragma unroll
      for (int db = 0; db < 4; db++) {
        half8 vf = *(const half8*)(Vc + db * 2048 + rb);
        oacc[db] = __builtin_amdgcn_mfma_f32_16x16x32_f16(vf, pf[kc].v, oacc[db], 0, 0, 0);
      }
    }
    cur ^= 1;
  }

  const int b = bh >> 4, h = bh & 15;
  float inv = 1.0f / lrun;
  int q = qw + l16;
#pragma unroll
  for (int db = 0; db < 4; db++) {
    half4 o;
    o[0] = (_Float16)(oacc[db][0] * inv);
    o[1] = (_Float16)(oacc[db][1] * inv);
    o[2] = (_Float16)(oacc[db][2] * inv);
    o[3] = (_Float16)(oacc[db][3] * inv);
    *(half4*)(AO + ((size_t)b * 2048 + q) * 1024 + h * 64 + db * 16 + lg * 4) = o;
  }
}

// ---------------- launch ----------------
extern "C" void kernel_launch(void* const* d_in, const int* in_sizes, int n_in,
                              void* d_out, int out_size, void* d_ws, size_t ws_size,
                              hipStream_t stream) {
  const float* x      = (const float*)d_in[0];  // (2,2048,1024)
  const float* qkv_w  = (const float*)d_in[1];  // (3072,1024)
  const float* proj_w = (const float*)d_in[2];  // (1024,1024)
  const float* proj_b = (const float*)d_in[3];  // (1024,)
  float* out = (float*)d_out;

  char* ws = (char*)d_ws;
  _Float16* Xh  = (_Float16*)(ws);                      // 4096x1024
  _Float16* Wq  = (_Float16*)(ws + ((size_t)8 << 20));  // 3072x1024
  _Float16* Wp  = (_Float16*)(ws + ((size_t)14 << 20)); // 1024x1024
  _Float16* Qb  = (_Float16*)(ws + ((size_t)16 << 20)); // 32x2048x64
  _Float16* Kb  = (_Float16*)(ws + ((size_t)24 << 20));
  _Float16* VbT = (_Float16*)(ws + ((size_t)32 << 20)); // 32x64x2048 (transposed, j-permuted)
  _Float16* AO  = (_Float16*)(ws + ((size_t)40 << 20)); // 4096x1024

  cast3_kernel<<<8192, 256, 0, stream>>>(x, qkv_w, proj_w, Xh);

  gemm_bt<0><<<dim3(24, 32), 256, 0, stream>>>(Xh, Wq, 1024, Qb, Kb, VbT, nullptr, nullptr);
  attn_kernel<<<dim3(32, 16), 512, 0, stream>>>(Qb, Kb, VbT, AO);
  gemm_bt<1><<<dim3(8, 32), 256, 0, stream>>>(AO, Wp, 1024, nullptr, nullptr, nullptr, out, proj_b);
}

// Round 7
// 187.746 us; speedup vs baseline: 1.4503x; 1.0717x over previous
//
#include <hip/hip_runtime.h>
#include <cstdint>

typedef __attribute__((ext_vector_type(8))) _Float16 half8;
typedef __attribute__((ext_vector_type(4))) _Float16 half4;
typedef __attribute__((ext_vector_type(2))) __fp16 fp16x2;
typedef __attribute__((ext_vector_type(4))) float f32x4;

union H8 { half8 v; unsigned u[4]; };
union H2U { fp16x2 h; unsigned u; };

__device__ __forceinline__ void gld_lds16(const void* g, void* l) {
  __builtin_amdgcn_global_load_lds(
      (const __attribute__((address_space(1))) unsigned int*)g,
      (__attribute__((address_space(3))) unsigned int*)l, 16, 0, 0);
}

// ---------------- fused cast fp32 -> fp16 (x | qkv_w | proj_w) ----------------
__global__ __launch_bounds__(256) void cast3_kernel(
    const float* __restrict__ x, const float* __restrict__ w1,
    const float* __restrict__ w2, _Float16* __restrict__ out) {
  int i = blockIdx.x * 256 + threadIdx.x;   // chunk of 4 floats
  const float* src;
  int off;
  if (i < 1048576)      { src = x;  off = i; }
  else if (i < 1835008) { src = w1; off = i - 1048576; }
  else                  { src = w2; off = i - 1835008; }
  float4 v = ((const float4*)src)[off];
  half4 h;
  h[0] = (_Float16)v.x; h[1] = (_Float16)v.y;
  h[2] = (_Float16)v.z; h[3] = (_Float16)v.w;
  ((half4*)out)[i] = h;
}

// ---------------- GEMM: C[M,N] = A[M,K] * B[N,K]^T (T2-swizzled LDS) ----------------
// EPI 0: scatter Q(*0.125)/K to [bh][s][64]; V TRANSPOSED to [bh][d][s']
// EPI 1: fp32 out + bias
template <int EPI>
__global__ __launch_bounds__(256) void gemm_bt(
    const _Float16* __restrict__ A, const _Float16* __restrict__ B, int K,
    _Float16* __restrict__ Qb, _Float16* __restrict__ Kb, _Float16* __restrict__ VbT,
    float* __restrict__ Out, const float* __restrict__ Bias) {
  __shared__ _Float16 Asm[128 * 64];
  __shared__ _Float16 Bsm[128 * 64];
  const int tid = threadIdx.x;
  const int wave = tid >> 6, lane = tid & 63;
  const int l16 = lane & 15, lg = lane >> 4;
  const int m0 = blockIdx.y * 128, n0 = blockIdx.x * 128;
  const int wr = wave >> 1, wc = wave & 1;
  f32x4 acc[4][4] = {};

  // staging source pre-swizzle: chunk cc -> cc ^ (row&7)
  int srow[4], sofs[4];
#pragma unroll
  for (int i = 0; i < 4; i++) {
    int c = tid + i * 256;
    srow[i] = c >> 3;
    sofs[i] = ((c & 7) ^ (srow[i] & 7)) * 8;
  }
  const int rb0 = ((lg) ^ (l16 & 7)) * 16;        // kc=0: chunk = lg
  const int rb1 = ((4 + lg) ^ (l16 & 7)) * 16;    // kc=1: chunk = 4+lg

  for (int k0 = 0; k0 < K; k0 += 64) {
    __syncthreads();
#pragma unroll
    for (int i = 0; i < 4; i++) {
      int c = tid + i * 256;
      gld_lds16(A + (size_t)(m0 + srow[i]) * K + k0 + sofs[i], (char*)Asm + c * 16);
      gld_lds16(B + (size_t)(n0 + srow[i]) * K + k0 + sofs[i], (char*)Bsm + c * 16);
    }
    __syncthreads();
#pragma unroll
    for (int kc = 0; kc < 2; kc++) {
      const int rb = kc ? rb1 : rb0;
      half8 af[4], bf[4];
#pragma unroll
      for (int f = 0; f < 4; f++) {
        af[f] = *(const half8*)((char*)Asm + (wr * 64 + f * 16 + l16) * 128 + rb);
        bf[f] = *(const half8*)((char*)Bsm + (wc * 64 + f * 16 + l16) * 128 + rb);
      }
#pragma unroll
      for (int i = 0; i < 4; i++)
#pragma unroll
        for (int j = 0; j < 4; j++)
          acc[i][j] = __builtin_amdgcn_mfma_f32_16x16x32_f16(af[i], bf[j], acc[i][j], 0, 0, 0);
    }
  }

  if (EPI == 0) {
#pragma unroll
    for (int i = 0; i < 4; i++) {
      int mbase = m0 + wr * 64 + i * 16 + lg * 4;    // 4-aligned
      int b = mbase >> 11, s = mbase & 2047;
#pragma unroll
      for (int j = 0; j < 4; j++) {
        int n = n0 + wc * 64 + j * 16 + l16;
        int part = n >> 10, f = n & 1023;
        int h = f >> 6, d = f & 63;
        if (part == 2) {
          int x = s & 31;
          int sp = (s & ~31) | (((x >> 2) & 3) << 3) | (((x >> 4) & 1) << 2);
          half4 v;
          v[0] = (_Float16)acc[i][j][0]; v[1] = (_Float16)acc[i][j][1];
          v[2] = (_Float16)acc[i][j][2]; v[3] = (_Float16)acc[i][j][3];
          *(half4*)(VbT + (((size_t)b * 16 + h) * 64 + d) * 2048 + sp) = v;
        } else {
          _Float16* dst = (part == 0) ? Qb : Kb;
          float scale = (part == 0) ? 0.125f : 1.0f;
#pragma unroll
          for (int r = 0; r < 4; r++)
            dst[(((size_t)b * 16 + h) * 2048 + (s + r)) * 64 + d] =
                (_Float16)(acc[i][j][r] * scale);
        }
      }
    }
  } else {
#pragma unroll
    for (int i = 0; i < 4; i++) {
      int mbase = m0 + wr * 64 + i * 16 + lg * 4;
#pragma unroll
      for (int j = 0; j < 4; j++) {
        int n = n0 + wc * 64 + j * 16 + l16;
        float bias = Bias[n];
#pragma unroll
        for (int r = 0; r < 4; r++) {
          int m = mbase + r;
          Out[(size_t)m * 1024 + n] = acc[i][j][r] + bias;
        }
      }
    }
  }
}

// ---------------- flash attention (prefix-causal), v4 ----------------
// grid (32 bh, 32 qtiles reversed); block 256 = 4 waves x 16 q-rows; KVBLK=64.
// Same per-wave structure as v3; smaller blocks -> 1024 blocks for occupancy
// (up to 5 blocks/CU, LDS-limited) and finer causal-tail granularity.
__global__ __launch_bounds__(256) void attn_kernel(
    const _Float16* __restrict__ Qb, const _Float16* __restrict__ Kb,
    const _Float16* __restrict__ VbT, _Float16* __restrict__ AO) {
  __shared__ _Float16 Ks[2][64 * 64];
  __shared__ _Float16 Vt[2][64 * 64];
  const int bh = blockIdx.x;
  const int q0 = (31 - blockIdx.y) * 64;   // heaviest blocks first
  const int tid = threadIdx.x, wave = tid >> 6, lane = tid & 63;
  const int l16 = lane & 15, lg = lane >> 4;
  const int qw = q0 + wave * 16;
  const size_t bhbase = (size_t)bh * 2048 * 64;
  const _Float16* Kbb = Kb + bhbase;
  const _Float16* Vbb = VbT + bhbase;

  // staging: lane-linear LDS dest, pre-swizzled global source (2 chunks each of K,V)
  const int c0 = tid, c1 = tid + 256;
  const int kofs0 = ((c0 >> 3) * 64) + (((c0 & 7) ^ ((c0 >> 3) & 7)) * 8);
  const int kofs1 = ((c1 >> 3) * 64) + (((c1 & 7) ^ ((c1 >> 3) & 7)) * 8);
  const int vofs0 = ((c0 >> 3) * 2048) + (((c0 & 7) ^ ((c0 >> 3) & 7)) * 8);
  const int vofs1 = ((c1 >> 3) * 2048) + (((c1 & 7) ^ ((c1 >> 3) & 7)) * 8);

  // Q fragments (B-operand rows q = qw + l16)
  half8 qf[2];
#pragma unroll
  for (int kc = 0; kc < 2; kc++)
    qf[kc] = *(const half8*)(Qb + bhbase + (size_t)(qw + l16) * 64 + kc * 32 + lg * 8);

  f32x4 oacc[4] = {};
  float mrun = -1e30f, lrun = 0.f;
  const int kend = (q0 + 64 > 256) ? (q0 + 64) : 256;

  const int xv = (l16 & 7) << 4;
  const int rb0 = l16 * 128 + ((lg * 16) ^ xv);
  const int rb1 = l16 * 128 + ((64 + lg * 16) ^ xv);

  auto STAGE = [&](int buf, int j0) {
    gld_lds16(Kbb + j0 * 64 + kofs0, (char*)Ks[buf] + c0 * 16);
    gld_lds16(Kbb + j0 * 64 + kofs1, (char*)Ks[buf] + c1 * 16);
    gld_lds16(Vbb + j0 + vofs0, (char*)Vt[buf] + c0 * 16);
    gld_lds16(Vbb + j0 + vofs1, (char*)Vt[buf] + c1 * 16);
  };

  STAGE(0, 0);
  int cur = 0;
  for (int j0 = 0; j0 < kend; j0 += 64) {
    __syncthreads();   // vmcnt(0) drain = wait for cur's stage; barrier
    if (j0 + 64 < kend) STAGE(cur ^ 1, j0 + 64);
    const char* Kc = (const char*)Ks[cur];
    const char* Vc = (const char*)Vt[cur];

    // S^T = K Q^T : lane holds S[q = qw+l16][j = j0+jb*16+lg*4+r]
    f32x4 sf[4] = {};
#pragma unroll
    for (int kc = 0; kc < 2; kc++) {
      const int rb = kc ? rb1 : rb0;
#pragma unroll
      for (int jb = 0; jb < 4; jb++) {
        half8 kf = *(const half8*)(Kc + jb * 2048 + rb);
        sf[jb] = __builtin_amdgcn_mfma_f32_16x16x32_f16(kf, qf[kc], sf[jb], 0, 0, 0);
      }
    }

    // prefix-causal mask: visible iff j <= s || j < 256
    if (j0 + 63 >= 256 && j0 + 63 > qw) {
      const int stok = qw + l16;
#pragma unroll
      for (int jb = 0; jb < 4; jb++)
#pragma unroll
        for (int r = 0; r < 4; r++) {
          int j = j0 + jb * 16 + lg * 4 + r;
          if (j > stok && j >= 256) sf[jb][r] = -1e30f;
        }
    }

    // row max: per-lane tree over 16 + 2 shfl (lanes sharing l16)
    float a0 = fmaxf(fmaxf(sf[0][0], sf[0][1]), fmaxf(sf[0][2], sf[0][3]));
    float a1 = fmaxf(fmaxf(sf[1][0], sf[1][1]), fmaxf(sf[1][2], sf[1][3]));
    float a2 = fmaxf(fmaxf(sf[2][0], sf[2][1]), fmaxf(sf[2][2], sf[2][3]));
    float a3 = fmaxf(fmaxf(sf[3][0], sf[3][1]), fmaxf(sf[3][2], sf[3][3]));
    float mt = fmaxf(fmaxf(a0, a1), fmaxf(a2, a3));
    mt = fmaxf(mt, __shfl_xor(mt, 16));
    mt = fmaxf(mt, __shfl_xor(mt, 32));

    // defer-max (T13): skip O-rescale while growth <= 8 nats-in-log2 units
    if (!__all(mt <= mrun + 5.545177f)) {
      float mn = fmaxf(mrun, mt);
      float corr = exp2f((mrun - mn) * 1.44269504f);
      mrun = mn;
      lrun *= corr;
#pragma unroll
      for (int db = 0; db < 4; db++) {
        oacc[db][0] *= corr; oacc[db][1] *= corr;
        oacc[db][2] *= corr; oacc[db][3] *= corr;
      }
    }
    const float nb = mrun * 1.44269504f;

    float p[16];
#pragma unroll
    for (int jb = 0; jb < 4; jb++)
#pragma unroll
      for (int r = 0; r < 4; r++)
        p[jb * 4 + r] = exp2f(sf[jb][r] * 1.44269504f - nb);

    float s0 = (p[0] + p[1]) + (p[2] + p[3]);
    float s1 = (p[4] + p[5]) + (p[6] + p[7]);
    float s2 = (p[8] + p[9]) + (p[10] + p[11]);
    float s3 = (p[12] + p[13]) + (p[14] + p[15]);
    float rs = (s0 + s1) + (s2 + s3);
    rs += __shfl_xor(rs, 16);
    rs += __shfl_xor(rs, 32);
    lrun += rs;

    // pack P to fp16; permuted-j layout makes this the exact B-fragment
    H8 pf[2];
#pragma unroll
    for (int kc = 0; kc < 2; kc++) {
      H2U t0, t1, t2, t3;
      t0.h = __builtin_amdgcn_cvt_pkrtz(p[kc * 8 + 0], p[kc * 8 + 1]);
      t1.h = __builtin_amdgcn_cvt_pkrtz(p[kc * 8 + 2], p[kc * 8 + 3]);
      t2.h = __builtin_amdgcn_cvt_pkrtz(p[kc * 8 + 4], p[kc * 8 + 5]);
      t3.h = __builtin_amdgcn_cvt_pkrtz(p[kc * 8 + 6], p[kc * 8 + 7]);
      pf[kc].u[0] = t0.u; pf[kc].u[1] = t1.u;
      pf[kc].u[2] = t2.u; pf[kc].u[3] = t3.u;
    }

    // O^T += V^T P : lane holds O[q = qw+l16][d = db*16+lg*4+r]
#pragma unroll
    for (int kc = 0; kc < 2; kc++) {
      const int rb = kc ? rb1 : rb0;
#pragma unroll
      for (int db = 0; db < 4; db++) {
        half8 vf = *(const half8*)(Vc + db * 2048 + rb);
        oacc[db] = __builtin_amdgcn_mfma_f32_16x16x32_f16(vf, pf[kc].v, oacc[db], 0, 0, 0);
      }
    }
    cur ^= 1;
  }

  const int b = bh >> 4, h = bh & 15;
  float inv = 1.0f / lrun;
  int q = qw + l16;
#pragma unroll
  for (int db = 0; db < 4; db++) {
    half4 o;
    o[0] = (_Float16)(oacc[db][0] * inv);
    o[1] = (_Float16)(oacc[db][1] * inv);
    o[2] = (_Float16)(oacc[db][2] * inv);
    o[3] = (_Float16)(oacc[db][3] * inv);
    *(half4*)(AO + ((size_t)b * 2048 + q) * 1024 + h * 64 + db * 16 + lg * 4) = o;
  }
}

// ---------------- launch ----------------
extern "C" void kernel_launch(void* const* d_in, const int* in_sizes, int n_in,
                              void* d_out, int out_size, void* d_ws, size_t ws_size,
                              hipStream_t stream) {
  const float* x      = (const float*)d_in[0];  // (2,2048,1024)
  const float* qkv_w  = (const float*)d_in[1];  // (3072,1024)
  const float* proj_w = (const float*)d_in[2];  // (1024,1024)
  const float* proj_b = (const float*)d_in[3];  // (1024,)
  float* out = (float*)d_out;

  char* ws = (char*)d_ws;
  _Float16* Xh  = (_Float16*)(ws);                      // 4096x1024
  _Float16* Wq  = (_Float16*)(ws + ((size_t)8 << 20));  // 3072x1024
  _Float16* Wp  = (_Float16*)(ws + ((size_t)14 << 20)); // 1024x1024
  _Float16* Qb  = (_Float16*)(ws + ((size_t)16 << 20)); // 32x2048x64
  _Float16* Kb  = (_Float16*)(ws + ((size_t)24 << 20));
  _Float16* VbT = (_Float16*)(ws + ((size_t)32 << 20)); // 32x64x2048 (transposed, j-permuted)
  _Float16* AO  = (_Float16*)(ws + ((size_t)40 << 20)); // 4096x1024

  cast3_kernel<<<8192, 256, 0, stream>>>(x, qkv_w, proj_w, Xh);

  gemm_bt<0><<<dim3(24, 32), 256, 0, stream>>>(Xh, Wq, 1024, Qb, Kb, VbT, nullptr, nullptr);
  attn_kernel<<<dim3(32, 32), 256, 0, stream>>>(Qb, Kb, VbT, AO);
  gemm_bt<1><<<dim3(8, 32), 256, 0, stream>>>(AO, Wp, 1024, nullptr, nullptr, nullptr, out, proj_b);
}